// Round 1
// baseline (1642.637 us; speedup 1.0000x reference)
//
#include <hip/hip_runtime.h>
#include <hip/hip_bf16.h>
#include <stdint.h>

// y[t][o] = sum_k x[t][k] * tanh(w[o][k])
// M=32768 (tokens), K=8192 (in), N=256 (out). Memory-bound: x fp32 read = 1.07 GB.
#define TOKENS  32768
#define IN_DIM  8192
#define OUT_DIM 256
#define BK      32
#define BM      128
#define XS_STRIDE (BK + 8)   // 40 ushort = 80 B rows (16B-aligned, breaks pow2 bank stride)

typedef __attribute__((ext_vector_type(8))) short bf16x8;   // MFMA A/B frag: 8 bf16
typedef __attribute__((ext_vector_type(4))) float f32x4;    // MFMA C/D frag

__device__ __forceinline__ unsigned short f2b(float f) {
    union { float f; unsigned int u; } c; c.f = f;
    unsigned int u = c.u + 0x7FFF + ((c.u >> 16) & 1);  // RNE
    return (unsigned short)(u >> 16);
}

// Kernel A: wb[o][k] = bf16(tanh(w[o][k])). 2M elems, float4 per thread.
__global__ __launch_bounds__(256) void tanh_bf16_kernel(const float* __restrict__ w,
                                                        unsigned short* __restrict__ wb) {
    const int i = (blockIdx.x * 256 + threadIdx.x) * 4;
    const float4 v = *(const float4*)(w + i);
    ushort4 o;
    o.x = f2b(tanhf(v.x));
    o.y = f2b(tanhf(v.y));
    o.z = f2b(tanhf(v.z));
    o.w = f2b(tanhf(v.w));
    *(ushort4*)(wb + i) = o;
}

// Kernel B: block = 256 threads (4 waves). Block tile: 128 rows x all 256 cols
// (x read exactly once from HBM). Wave w handles n in [w*64, w*64+64).
// Per K-step: stage x (fp32->bf16) and w tiles to LDS from regs prefetched
// during the previous step's MFMA phase.
__global__ __launch_bounds__(256, 1) void gemm_kernel(const float* __restrict__ x,
                                                      const unsigned short* __restrict__ wb,
                                                      float* __restrict__ out) {
    __shared__ __align__(16) unsigned short xs[BM * XS_STRIDE];   // 10240 B
    __shared__ __align__(16) unsigned short wt[OUT_DIM * BK];     // 16384 B

    const int tid  = threadIdx.x;
    const int wave = tid >> 6;
    const int lane = tid & 63;
    const int lrow = lane & 15;   // m (A) / n (B) / col (C) within 16-tile
    const int quad = lane >> 4;   // k-quad for A/B; row-quad for C
    const long m0  = (long)blockIdx.x * BM;

    // x staging: round r: row = r*32 + (tid>>3), col = (tid&7)*4  (float4)
    const int xrow = tid >> 3;
    const int xcol = (tid & 7) * 4;
    // w staging: round r: o = r*64 + (tid>>2), k' = (tid&3)*8  (uint4 = 8 bf16)
    const int wrow = tid >> 2;
    const int wcol = (tid & 3) * 8;

    const float*          xg = x  + (m0 + xrow) * IN_DIM + xcol;
    const unsigned short* wg = wb + (long)wrow * IN_DIM + wcol;

    float4 xv[4];
    uint4  wv[4];
#pragma unroll
    for (int r = 0; r < 4; ++r) xv[r] = *(const float4*)(xg + (long)r * 32 * IN_DIM);
#pragma unroll
    for (int r = 0; r < 4; ++r) wv[r] = *(const uint4*)(wg + (long)r * 64 * IN_DIM);

    f32x4 acc[8][4];
#pragma unroll
    for (int mt = 0; mt < 8; ++mt)
#pragma unroll
        for (int nt = 0; nt < 4; ++nt)
            acc[mt][nt] = (f32x4){0.f, 0.f, 0.f, 0.f};

    const int NSTEP = IN_DIM / BK;   // 256
    for (int s = 0; s < NSTEP; ++s) {
        // write staged regs -> LDS
#pragma unroll
        for (int r = 0; r < 4; ++r) {
            ushort4 b;
            b.x = f2b(xv[r].x); b.y = f2b(xv[r].y);
            b.z = f2b(xv[r].z); b.w = f2b(xv[r].w);
            *(ushort4*)&xs[(r * 32 + xrow) * XS_STRIDE + xcol] = b;
        }
#pragma unroll
        for (int r = 0; r < 4; ++r)
            *(uint4*)&wt[(r * 64 + wrow) * BK + wcol] = wv[r];
        __syncthreads();

        // prefetch next K-step into regs (wraps harmlessly on last iter);
        // latency hides under the MFMA phase below, drained by the end barrier.
        const int kn = ((s + 1) * BK) & (IN_DIM - 1);
#pragma unroll
        for (int r = 0; r < 4; ++r)
            xv[r] = *(const float4*)(xg + (long)r * 32 * IN_DIM + kn - xcol + xcol); // keep addr simple
#pragma unroll
        for (int r = 0; r < 4; ++r)
            wv[r] = *(const uint4*)(wg + (long)r * 64 * IN_DIM + kn);

        // compute: 4 B-frags (this wave's 64 cols), 8 A-frags, 32 MFMAs
        bf16x8 bfr[4];
#pragma unroll
        for (int nt = 0; nt < 4; ++nt)
            bfr[nt] = *(const bf16x8*)&wt[(wave * 64 + nt * 16 + lrow) * BK + quad * 8];
#pragma unroll
        for (int mt = 0; mt < 8; ++mt) {
            bf16x8 afr = *(const bf16x8*)&xs[(mt * 16 + lrow) * XS_STRIDE + quad * 8];
#pragma unroll
            for (int nt = 0; nt < 4; ++nt)
                acc[mt][nt] = __builtin_amdgcn_mfma_f32_16x16x32_bf16(afr, bfr[nt], acc[mt][nt], 0, 0, 0);
        }
        __syncthreads();
    }

    // Epilogue. C/D layout (verified m89/m91): col = lane&15, row = quad*4 + reg.
    float* og = out + (m0 + quad * 4) * OUT_DIM + wave * 64 + lrow;
#pragma unroll
    for (int mt = 0; mt < 8; ++mt)
#pragma unroll
        for (int nt = 0; nt < 4; ++nt)
#pragma unroll
            for (int i = 0; i < 4; ++i)
                og[(long)(mt * 16 + i) * OUT_DIM + nt * 16] = acc[mt][nt][i];
}

extern "C" void kernel_launch(void* const* d_in, const int* in_sizes, int n_in,
                              void* d_out, int out_size, void* d_ws, size_t ws_size,
                              hipStream_t stream) {
    const float* xp = (const float*)d_in[0];      // [32768, 8192] fp32
    const float* wp = (const float*)d_in[1];      // [256, 8192] fp32
    float* op = (float*)d_out;                    // [32768, 256] fp32
    unsigned short* wb = (unsigned short*)d_ws;   // 4 MB bf16(tanh(w)); ws re-poisoned each call

    tanh_bf16_kernel<<<(OUT_DIM * IN_DIM / 4) / 256, 256, 0, stream>>>(wp, wb);
    gemm_kernel<<<TOKENS / BM, 256, 0, stream>>>(xp, wb, op);
}